// Round 2
// baseline (62.711 us; speedup 1.0000x reference)
//
#include <hip/hip_runtime.h>
#include <hip/hip_bf16.h>

// Problem: out[b] = w_bias + sum_{s=0}^{S-1} w_weight[ text[s][b] ]
//   text: (S=200, B=2048) int32, values in [0, 50000)
//   w_weight: (1, V=50000) f32; w_bias: (1,) f32; out: (B,1) f32
//
// Round 2: single launch, no memset, no atomics. Each block fully owns 16
// phrases (16 threads per phrase, s strided by 16), LDS tree-reduce, direct
// store of bias+sum. 128 blocks spread the 409600 random gathers across
// 128 CUs (~3200 transactions/CU); the 200 KB w table is L2-resident.
// d_out poison is irrelevant since every element is written exactly once.

#define SS 200
#define BB 2048
#define PHRASES_PER_BLOCK 16   // grid = 2048/16 = 128 blocks
#define SGROUPS 16             // threads per phrase

__global__ __launch_bounds__(256) void MNB_455266533601_kernel(
    const int* __restrict__ text,
    const float* __restrict__ w,
    const float* __restrict__ bias,
    float* __restrict__ out)
{
    const int tid     = threadIdx.x;
    const int b_local = tid & (PHRASES_PER_BLOCK - 1);   // 0..15
    const int g       = tid >> 4;                        // s-group 0..15
    const int b       = blockIdx.x * PHRASES_PER_BLOCK + b_local;

    // Each thread: tokens s = g, g+16, g+32, ... (13 for g<8, 12 for g>=8).
    // Lanes 0..15 of a segment read 16 consecutive b of one s-row -> 64B seg.
    float sum = 0.0f;
    for (int s = g; s < SS; s += SGROUPS) {
        const int idx = text[s * BB + b];
        sum += w[idx];                       // random gather, L2-resident
    }

    __shared__ float part[256];              // part[g*16 + b_local]
    part[tid] = sum;
    __syncthreads();

    // Tree-reduce over the 16 s-groups (stride in units of 16 threads).
#pragma unroll
    for (int off = 128; off >= 16; off >>= 1) {
        if (tid < off) part[tid] += part[tid + off];
        __syncthreads();
    }

    if (tid < PHRASES_PER_BLOCK) {
        out[blockIdx.x * PHRASES_PER_BLOCK + tid] = part[tid] + bias[0];
    }
}

extern "C" void kernel_launch(void* const* d_in, const int* in_sizes, int n_in,
                              void* d_out, int out_size, void* d_ws, size_t ws_size,
                              hipStream_t stream) {
    const int*   text = (const int*)  d_in[0];   // 409600
    const float* w    = (const float*)d_in[1];   // 50000
    const float* bias = (const float*)d_in[2];   // 1
    float* out = (float*)d_out;                  // 2048

    dim3 grid(BB / PHRASES_PER_BLOCK, 1, 1);     // 128 blocks
    dim3 block(256, 1, 1);
    MNB_455266533601_kernel<<<grid, block, 0, stream>>>(text, w, bias, out);
}

// Round 3
// 60.775 us; speedup vs baseline: 1.0319x; 1.0319x over previous
//
#include <hip/hip_runtime.h>
#include <hip/hip_bf16.h>

// Problem: out[b] = w_bias + sum_{s=0}^{S-1} w_weight[ text[s][b] ]
//   text: (S=200, B=2048) int32; w_weight: (V=50000,) f32; w_bias: (1,) f32
//
// Round 3: latency-optimal calibration. Harness floor analysis: the 256 MB
// d_ws re-poison alone is 41 us at 82% HBM peak inside every timed iter.
// Kernel goal: minimize our slice. 400 blocks (all 256 CUs busy), constant
// trip count 4 fully unrolled -> 4 independent text loads then 4 independent
// w-gathers (two latency waves, not a dependent chain). One float atomicAdd
// per thread (50 per address, negligible contention). d_out is poisoned
// 0xAA every iter -> zero it with hipMemsetAsync (8 KB, ~2 us).

#define SS 200
#define BB 2048
#define CHUNK 4            // s per thread; grid.y = SS/CHUNK = 50

__global__ __launch_bounds__(256) void MNB_455266533601_kernel(
    const int* __restrict__ text,
    const float* __restrict__ w,
    const float* __restrict__ bias,
    float* __restrict__ out)
{
    const int b  = blockIdx.x * 256 + threadIdx.x;  // grid.x = 8
    const int s0 = blockIdx.y * CHUNK;

    // 4 independent coalesced text loads (1 KB per wave-row each).
    int idx0 = text[(s0 + 0) * BB + b];
    int idx1 = text[(s0 + 1) * BB + b];
    int idx2 = text[(s0 + 2) * BB + b];
    int idx3 = text[(s0 + 3) * BB + b];

    // 4 independent random gathers into the L2-resident 200 KB table.
    float sum = w[idx0] + w[idx1] + w[idx2] + w[idx3];

    if (blockIdx.y == 0) sum += bias[0];
    atomicAdd(&out[b], sum);
}

extern "C" void kernel_launch(void* const* d_in, const int* in_sizes, int n_in,
                              void* d_out, int out_size, void* d_ws, size_t ws_size,
                              hipStream_t stream) {
    const int*   text = (const int*)  d_in[0];   // 409600
    const float* w    = (const float*)d_in[1];   // 50000
    const float* bias = (const float*)d_in[2];   // 1
    float* out = (float*)d_out;                  // 2048

    hipMemsetAsync(out, 0, (size_t)out_size * sizeof(float), stream);

    dim3 grid(BB / 256, SS / CHUNK, 1);          // (8, 50) = 400 blocks
    dim3 block(256, 1, 1);
    MNB_455266533601_kernel<<<grid, block, 0, stream>>>(text, w, bias, out);
}